// Round 1
// 317.184 us; speedup vs baseline: 1.0536x; 1.0536x over previous
//
#include <hip/hip_runtime.h>
#include <stdint.h>

#define DEV static __device__ __forceinline__

typedef __bf16 bf16_t;
typedef bf16_t bf16x8 __attribute__((ext_vector_type(8)));
typedef bf16_t bf16x4 __attribute__((ext_vector_type(4)));
typedef float f32x4 __attribute__((ext_vector_type(4)));

static constexpr int Bc = 4, Sc = 2048, Dc = 1024, Hc = 16, DKc = 64;
static constexpr int Mrows = Bc * Sc; // 8192

DEV unsigned short f2bf(float f) {
  unsigned int u = __float_as_uint(f);
  u += 0x7fffu + ((u >> 16) & 1u);
  return (unsigned short)(u >> 16);
}

DEV float fexp2(float x) { return exp2f(x); } // v_exp_f32 at -O3

DEV void gload_lds16(const void* g, void* l) {
  __builtin_amdgcn_global_load_lds(
      (const __attribute__((address_space(1))) void*)g,
      (__attribute__((address_space(3))) void*)l, 16, 0, 0);
}

// ---------------- fp32 -> bf16 conversion ----------------
__global__ void __launch_bounds__(256) cvt_bf16_kernel(
    const float* __restrict__ in, unsigned short* __restrict__ out, int n4) {
  int i = blockIdx.x * blockDim.x + threadIdx.x;
  if (i < n4) {
    float4 v = reinterpret_cast<const float4*>(in)[i];
    ushort4 o;
    o.x = f2bf(v.x); o.y = f2bf(v.y); o.z = f2bf(v.z); o.w = f2bf(v.w);
    reinterpret_cast<ushort4*>(out)[i] = o;
  }
}

// ---------------- GEMM: C[m][n] = (sum_k A[m][k]*W[n][k] + bias[n]) * scale ----
// A: [M][K] bf16 row-major, W: [N][K] bf16 row-major (i.e. X @ W^T)
// 128x128 tile, BK=32, 256 threads (4 waves, 2x2), 4x4 16x16x32 MFMA per wave.
// MODE: 0 = f32 linear out, 1 = bf16 linear out,
//       2 = bf16 TRANSPOSED out: Cout[(b*Dc + n)*Sc + s], m = b*Sc + s
//           (pre-transposed V so attention can stage V^T via global_load_lds)
template <int MODE>
__global__ void __launch_bounds__(256) gemm_bt_kernel(
    const unsigned short* __restrict__ A, const unsigned short* __restrict__ W,
    const float* __restrict__ bias, void* __restrict__ Cout,
    int M, int N, int K, float scale) {
  __shared__ unsigned short lA[128 * 32];
  __shared__ unsigned short lB[128 * 32];
  const int t = threadIdx.x;
  const int wv = t >> 6, ln = t & 63;
  const int l15 = ln & 15, lhi = ln >> 4;
  const int m0 = blockIdx.y * 128, n0 = blockIdx.x * 128;
  const int wr = wv >> 1, wc = wv & 1;

  f32x4 acc[4][4] = {};

  for (int k0 = 0; k0 < K; k0 += 32) {
    __syncthreads();
#pragma unroll
    for (int r = 0; r < 2; ++r) {
      int e = r * 2048 + t * 8;
      int row = e >> 5, col = e & 31;
      gload_lds16(A + (size_t)(m0 + row) * K + k0 + col, (char*)lA + e * 2);
      gload_lds16(W + (size_t)(n0 + row) * K + k0 + col, (char*)lB + e * 2);
    }
    __syncthreads();
    bf16x8 af[4], bfr[4];
#pragma unroll
    for (int i = 0; i < 4; ++i)
      af[i] = *reinterpret_cast<const bf16x8*>(&lA[(wr * 64 + i * 16 + l15) * 32 + lhi * 8]);
#pragma unroll
    for (int j = 0; j < 4; ++j)
      bfr[j] = *reinterpret_cast<const bf16x8*>(&lB[(wc * 64 + j * 16 + l15) * 32 + lhi * 8]);
#pragma unroll
    for (int i = 0; i < 4; ++i)
#pragma unroll
      for (int j = 0; j < 4; ++j)
        acc[i][j] = __builtin_amdgcn_mfma_f32_16x16x32_bf16(af[i], bfr[j], acc[i][j], 0, 0, 0);
  }

#pragma unroll
  for (int i = 0; i < 4; ++i)
#pragma unroll
    for (int j = 0; j < 4; ++j) {
      int n = n0 + wc * 64 + j * 16 + l15;
      float bv = bias[n];
      if (MODE == 2) {
        int mb = m0 + wr * 64 + i * 16 + lhi * 4; // 4 consecutive m = consecutive s
        ushort4 ov;
        ov.x = f2bf((acc[i][j][0] + bv) * scale);
        ov.y = f2bf((acc[i][j][1] + bv) * scale);
        ov.z = f2bf((acc[i][j][2] + bv) * scale);
        ov.w = f2bf((acc[i][j][3] + bv) * scale);
        *reinterpret_cast<ushort4*>((unsigned short*)Cout +
            ((size_t)(mb >> 11) * Dc + n) * Sc + (mb & (Sc - 1))) = ov;
      } else {
#pragma unroll
        for (int jj = 0; jj < 4; ++jj) {
          int m = m0 + wr * 64 + i * 16 + lhi * 4 + jj;
          float v = (acc[i][j][jj] + bv) * scale;
          if (MODE == 1)
            ((unsigned short*)Cout)[(size_t)m * N + n] = f2bf(v);
          else
            ((float*)Cout)[(size_t)m * N + n] = v;
        }
      }
    }
}

// ---------------- Flash attention ----------------
// Q prescaled by log2(e)/sqrt(DK) (softmax in exp2 domain).
// Q/K/X: [B*S][D] bf16; head h = columns [h*64, h*64+64).
// Vt: [B*D][S] bf16 (pre-transposed by the V-projection GEMM).
// Block = (b, h, 64 q-rows); 4 waves x 16 q-rows each.
// Pipeline: double-buffered K/V^T tiles in LDS; next tile's global_load_lds
// issued BEFORE current tile's compute; single vmcnt(0)+s_barrier per tile
// (the "minimum 2-phase" schedule) so HBM/L2 latency hides under compute.
// Swapped QK^T: sacc = mfma(K, Q) so each lane's regs hold scores of ONE
// q-row (l15): kv = ct*16 + lhi*4 + jj. Row-reduce = shfl_xor(16,32) only.
// Defer-max (THR=8, exp2 domain): skip O-rescale unless the tile max grew.
__global__ void __launch_bounds__(256) attn_kernel(
    const unsigned short* __restrict__ Q, const unsigned short* __restrict__ Kk,
    const unsigned short* __restrict__ Vt, unsigned short* __restrict__ X) {
  __shared__ unsigned short lK[2][64 * 64];   // [kv][dk], XOR-swizzled (both-sides)
  __shared__ unsigned short lVT[2][64 * 64];  // [dk][kv], XOR-swizzled
  __shared__ unsigned short lP[4 * 16 * 64];  // per-wave [16][64], XOR-swizzled
  const int t = threadIdx.x;
  const int wv = t >> 6, ln = t & 63;
  const int l15 = ln & 15, lhi = ln >> 4;
  const int q0 = blockIdx.x * 64;
  const int h = blockIdx.y, b = blockIdx.z;
  const size_t base = (size_t)b * Sc * Dc;
  const int hoff = h * DKc;

  bf16x8 qf[2];
  {
    const unsigned short* qp = Q + base + (size_t)(q0 + wv * 16 + l15) * Dc + hoff + lhi * 8;
    qf[0] = *reinterpret_cast<const bf16x8*>(qp);
    qf[1] = *reinterpret_cast<const bf16x8*>(qp + 32);
  }

  // staging thread roles: both K and V^T tiles are 64x64 elems, 2 chunks each.
  // LDS dest is LINEAR (global_load_lds constraint); swizzle applied on SOURCE col.
  const int e0 = t * 8, e1 = 2048 + t * 8;
  const int r0 = e0 >> 6, c0 = (e0 & 63) ^ ((r0 & 7) << 3);
  const int r1 = e1 >> 6, c1 = (e1 & 63) ^ ((r1 & 7) << 3);
  const unsigned short* kS0 = Kk + base + (size_t)r0 * Dc + hoff + c0;
  const unsigned short* kS1 = Kk + base + (size_t)r1 * Dc + hoff + c1;
  const unsigned short* vS0 = Vt + ((size_t)b * Dc + hoff + r0) * Sc + c0;
  const unsigned short* vS1 = Vt + ((size_t)b * Dc + hoff + r1) * Sc + c1;

  float mrow = -1e30f, lrow = 0.f; // running max/sum for q-row l15 (x4 replicated)
  f32x4 xacc[4] = {};              // out rows lhi*4+jj, cols dt*16+l15
  const int swzK = (l15 & 7) << 4;

#define STAGE(bi, kv0_)                                                    \
  do {                                                                     \
    size_t ko = (size_t)(kv0_) * Dc;                                       \
    gload_lds16(kS0 + ko, (char*)lK[bi] + e0 * 2);                         \
    gload_lds16(kS1 + ko, (char*)lK[bi] + e1 * 2);                         \
    gload_lds16(vS0 + (kv0_), (char*)lVT[bi] + e0 * 2);                    \
    gload_lds16(vS1 + (kv0_), (char*)lVT[bi] + e1 * 2);                    \
  } while (0)

  STAGE(0, 0);
  asm volatile("s_waitcnt vmcnt(0)" ::: "memory");
  __builtin_amdgcn_s_barrier();
  __builtin_amdgcn_sched_barrier(0);

  for (int tt = 0; tt < Sc / 64; ++tt) {
    const int cur = tt & 1;
    if (tt + 1 < Sc / 64) STAGE(cur ^ 1, (tt + 1) * 64); // prefetch next tile

    const unsigned short* K_ = lK[cur];
    const unsigned short* VT_ = lVT[cur];

    // swapped QK^T: sacc[ct][jj] = S[kv0 + ct*16 + lhi*4 + jj][q-row l15]
    f32x4 sacc[4];
#pragma unroll
    for (int ct = 0; ct < 4; ++ct) {
      f32x4 z = {};
#pragma unroll
      for (int kk = 0; kk < 2; ++kk) {
        bf16x8 kf = *reinterpret_cast<const bf16x8*>(
            (const char*)K_ + (((ct * 16 + l15) * 128 + kk * 64 + lhi * 16) ^ swzK));
        z = __builtin_amdgcn_mfma_f32_16x16x32_bf16(kf, qf[kk], z, 0, 0, 0);
      }
      sacc[ct] = z;
    }

    // tile max for q-row l15
    float mc[4];
#pragma unroll
    for (int ct = 0; ct < 4; ++ct)
      mc[ct] = fmaxf(fmaxf(sacc[ct][0], sacc[ct][1]), fmaxf(sacc[ct][2], sacc[ct][3]));
    float mt = fmaxf(fmaxf(mc[0], mc[1]), fmaxf(mc[2], mc[3]));
    mt = fmaxf(mt, __shfl_xor(mt, 16));
    mt = fmaxf(mt, __shfl_xor(mt, 32));

    // defer-max: rescale only when some row's max grew past threshold.
    // With stale m, P <= 2^8 = 256 — harmless in f32 accum / bf16 P.
    if (__any(mt > mrow + 8.0f)) {
      float mnew = fmaxf(mrow, mt);
      float corr = fexp2(mrow - mnew);
      mrow = mnew;
      lrow *= corr;
#pragma unroll
      for (int jj = 0; jj < 4; ++jj) {
        float cO = __shfl(corr, lhi * 4 + jj);
#pragma unroll
        for (int dt = 0; dt < 4; ++dt) xacc[dt][jj] *= cO;
      }
    }

    float rs = 0.f;
#pragma unroll
    for (int ct = 0; ct < 4; ++ct) {
      bf16x4 pv;
#pragma unroll
      for (int jj = 0; jj < 4; ++jj) {
        float p = fexp2(sacc[ct][jj] - mrow);
        rs += p;
        pv[jj] = (bf16_t)p;
      }
      *reinterpret_cast<bf16x4*>(
          (char*)lP + ((wv * 2048 + l15 * 128 + ct * 32 + lhi * 8) ^ swzK)) = pv;
    }
    rs += __shfl_xor(rs, 16);
    rs += __shfl_xor(rs, 32);
    lrow += rs;

    // PV: xacc[dt] += P(16x64) @ V^T(64x16)
#pragma unroll
    for (int kk = 0; kk < 2; ++kk) {
      bf16x8 pa = *reinterpret_cast<const bf16x8*>(
          (char*)lP + ((wv * 2048 + l15 * 128 + kk * 64 + lhi * 16) ^ swzK));
#pragma unroll
      for (int dt = 0; dt < 4; ++dt) {
        bf16x8 vb = *reinterpret_cast<const bf16x8*>(
            (const char*)VT_ + (((dt * 16 + l15) * 128 + kk * 64 + lhi * 16) ^ swzK));
        xacc[dt] = __builtin_amdgcn_mfma_f32_16x16x32_bf16(pa, vb, xacc[dt], 0, 0, 0);
      }
    }

    // single drain+barrier per tile: prefetch loads had the whole compute
    // phase to land; next iteration overwrites the buffer everyone just read.
    asm volatile("s_waitcnt vmcnt(0)" ::: "memory");
    __builtin_amdgcn_s_barrier();
    __builtin_amdgcn_sched_barrier(0);
  }
#undef STAGE

  float linv = 1.0f / lrow; // inverse sum for q-row l15
  float iO[4];
#pragma unroll
  for (int jj = 0; jj < 4; ++jj) iO[jj] = __shfl(linv, lhi * 4 + jj);

  unsigned short* xp = X + base + (size_t)(q0 + wv * 16) * Dc + hoff;
#pragma unroll
  for (int dt = 0; dt < 4; ++dt)
#pragma unroll
    for (int jj = 0; jj < 4; ++jj) {
      int r = lhi * 4 + jj;
      xp[(size_t)r * Dc + dt * 16 + l15] = f2bf(xacc[dt][jj] * iO[jj]);
    }
}

// ---------------- launch ----------------
extern "C" void kernel_launch(void* const* d_in, const int* in_sizes, int n_in,
                              void* d_out, int out_size, void* d_ws, size_t ws_size,
                              hipStream_t stream) {
  const float* query = (const float*)d_in[0];
  const float* key   = (const float*)d_in[1];
  const float* value = (const float*)d_in[2];
  const float* Wq = (const float*)d_in[3];
  const float* bq = (const float*)d_in[4];
  const float* Wk = (const float*)d_in[5];
  const float* bk = (const float*)d_in[6];
  const float* Wv = (const float*)d_in[7];
  const float* bv = (const float*)d_in[8];
  const float* Wo = (const float*)d_in[9];
  const float* bo = (const float*)d_in[10];

  const size_t NBS = (size_t)Mrows * Dc; // 8388608
  const size_t NW  = (size_t)Dc * Dc;    // 1048576
  unsigned short* bQin = (unsigned short*)d_ws;
  unsigned short* bKin = bQin + NBS;
  unsigned short* bVin = bKin + NBS;
  unsigned short* bWq  = bVin + NBS;
  unsigned short* bWk  = bWq + NW;
  unsigned short* bWv  = bWk + NW;
  unsigned short* bWo  = bWv + NW;
  unsigned short* Qp   = bWo + NW;
  unsigned short* Kp   = Qp + NBS;
  unsigned short* Vtp  = Kp + NBS; // V projection stored TRANSPOSED: [B*D][S]
  unsigned short* Xp   = Vtp + NBS;

  cvt_bf16_kernel<<<(int)(NBS / 1024), 256, 0, stream>>>(query, bQin, (int)(NBS / 4));
  cvt_bf16_kernel<<<(int)(NBS / 1024), 256, 0, stream>>>(key,   bKin, (int)(NBS / 4));
  cvt_bf16_kernel<<<(int)(NBS / 1024), 256, 0, stream>>>(value, bVin, (int)(NBS / 4));
  cvt_bf16_kernel<<<(int)(NW / 1024),  256, 0, stream>>>(Wq, bWq, (int)(NW / 4));
  cvt_bf16_kernel<<<(int)(NW / 1024),  256, 0, stream>>>(Wk, bWk, (int)(NW / 4));
  cvt_bf16_kernel<<<(int)(NW / 1024),  256, 0, stream>>>(Wv, bWv, (int)(NW / 4));
  cvt_bf16_kernel<<<(int)(NW / 1024),  256, 0, stream>>>(Wo, bWo, (int)(NW / 4));

  dim3 gg(Dc / 128, Mrows / 128); // (8, 64)
  // Q prescale folds 1/sqrt(DK) AND log2(e) (attn softmax runs in exp2 domain)
  gemm_bt_kernel<1><<<gg, 256, 0, stream>>>(bQin, bWq, bq, Qp, Mrows, Dc, Dc,
                                            0.125f * 1.44269504088896340736f);
  gemm_bt_kernel<1><<<gg, 256, 0, stream>>>(bKin, bWk, bk, Kp, Mrows, Dc, Dc, 1.0f);
  gemm_bt_kernel<2><<<gg, 256, 0, stream>>>(bVin, bWv, bv, Vtp, Mrows, Dc, Dc, 1.0f);

  attn_kernel<<<dim3(Sc / 64, Hc, Bc), 256, 0, stream>>>(Qp, Kp, Vtp, Xp);

  gemm_bt_kernel<0><<<gg, 256, 0, stream>>>(Xp, bWo, bo, d_out, Mrows, Dc, Dc, 1.0f);
}

// Round 2
// 274.109 us; speedup vs baseline: 1.2192x; 1.1571x over previous
//
#include <hip/hip_runtime.h>
#include <stdint.h>

#define DEV static __device__ __forceinline__

typedef __bf16 bf16_t;
typedef bf16_t bf16x8 __attribute__((ext_vector_type(8)));
typedef bf16_t bf16x4 __attribute__((ext_vector_type(4)));
typedef float f32x4 __attribute__((ext_vector_type(4)));

static constexpr int Bc = 4, Sc = 2048, Dc = 1024, Hc = 16, DKc = 64;
static constexpr int Mrows = Bc * Sc; // 8192

DEV unsigned short f2bf(float f) {
  unsigned int u = __float_as_uint(f);
  u += 0x7fffu + ((u >> 16) & 1u);
  return (unsigned short)(u >> 16);
}

DEV float fexp2(float x) {
#if __has_builtin(__builtin_amdgcn_exp2f)
  return __builtin_amdgcn_exp2f(x); // single v_exp_f32, no libm wrapper
#else
  return exp2f(x);
#endif
}

DEV void gload_lds16(const void* g, void* l) {
  __builtin_amdgcn_global_load_lds(
      (const __attribute__((address_space(1))) void*)g,
      (__attribute__((address_space(3))) void*)l, 16, 0, 0);
}

// ---------------- fp32 -> bf16 conversion ----------------
__global__ void __launch_bounds__(256) cvt_bf16_kernel(
    const float* __restrict__ in, unsigned short* __restrict__ out, int n4) {
  int i = blockIdx.x * blockDim.x + threadIdx.x;
  if (i < n4) {
    float4 v = reinterpret_cast<const float4*>(in)[i];
    ushort4 o;
    o.x = f2bf(v.x); o.y = f2bf(v.y); o.z = f2bf(v.z); o.w = f2bf(v.w);
    reinterpret_cast<ushort4*>(out)[i] = o;
  }
}

// ---------------- GEMM: C[m][n] = (sum_k A[m][k]*W[n][k] + bias[n]) * scale ----
// A: [M][K] bf16 row-major, W: [N][K] bf16 row-major (i.e. X @ W^T)
// 128x128 tile, BK=32, 256 threads (4 waves, 2x2), 4x4 16x16x32 MFMA per wave.
// MODE: 0 = f32 linear out, 1 = bf16 linear out,
//       2 = bf16 TRANSPOSED out: Cout[(b*Dc + n)*Sc + s], m = b*Sc + s
template <int MODE>
__global__ void __launch_bounds__(256) gemm_bt_kernel(
    const unsigned short* __restrict__ A, const unsigned short* __restrict__ W,
    const float* __restrict__ bias, void* __restrict__ Cout,
    int M, int N, int K, float scale) {
  __shared__ unsigned short lA[128 * 32];
  __shared__ unsigned short lB[128 * 32];
  const int t = threadIdx.x;
  const int wv = t >> 6, ln = t & 63;
  const int l15 = ln & 15, lhi = ln >> 4;
  const int m0 = blockIdx.y * 128, n0 = blockIdx.x * 128;
  const int wr = wv >> 1, wc = wv & 1;

  f32x4 acc[4][4] = {};

  for (int k0 = 0; k0 < K; k0 += 32) {
    __syncthreads();
#pragma unroll
    for (int r = 0; r < 2; ++r) {
      int e = r * 2048 + t * 8;
      int row = e >> 5, col = e & 31;
      gload_lds16(A + (size_t)(m0 + row) * K + k0 + col, (char*)lA + e * 2);
      gload_lds16(W + (size_t)(n0 + row) * K + k0 + col, (char*)lB + e * 2);
    }
    __syncthreads();
    bf16x8 af[4], bfr[4];
#pragma unroll
    for (int i = 0; i < 4; ++i)
      af[i] = *reinterpret_cast<const bf16x8*>(&lA[(wr * 64 + i * 16 + l15) * 32 + lhi * 8]);
#pragma unroll
    for (int j = 0; j < 4; ++j)
      bfr[j] = *reinterpret_cast<const bf16x8*>(&lB[(wc * 64 + j * 16 + l15) * 32 + lhi * 8]);
#pragma unroll
    for (int i = 0; i < 4; ++i)
#pragma unroll
      for (int j = 0; j < 4; ++j)
        acc[i][j] = __builtin_amdgcn_mfma_f32_16x16x32_bf16(af[i], bfr[j], acc[i][j], 0, 0, 0);
  }

#pragma unroll
  for (int i = 0; i < 4; ++i)
#pragma unroll
    for (int j = 0; j < 4; ++j) {
      int n = n0 + wc * 64 + j * 16 + l15;
      float bv = bias[n];
      if (MODE == 2) {
        int mb = m0 + wr * 64 + i * 16 + lhi * 4; // 4 consecutive m = consecutive s
        ushort4 ov;
        ov.x = f2bf((acc[i][j][0] + bv) * scale);
        ov.y = f2bf((acc[i][j][1] + bv) * scale);
        ov.z = f2bf((acc[i][j][2] + bv) * scale);
        ov.w = f2bf((acc[i][j][3] + bv) * scale);
        *reinterpret_cast<ushort4*>((unsigned short*)Cout +
            ((size_t)(mb >> 11) * Dc + n) * Sc + (mb & (Sc - 1))) = ov;
      } else {
#pragma unroll
        for (int jj = 0; jj < 4; ++jj) {
          int m = m0 + wr * 64 + i * 16 + lhi * 4 + jj;
          float v = (acc[i][j][jj] + bv) * scale;
          if (MODE == 1)
            ((unsigned short*)Cout)[(size_t)m * N + n] = f2bf(v);
          else
            ((float*)Cout)[(size_t)m * N + n] = v;
        }
      }
    }
}

// ---------------- Flash attention ----------------
// Q prescaled by log2(e)/sqrt(DK) (softmax in exp2 domain).
// Q/K/X: [B*S][D] bf16; head h = columns [h*64, h*64+64).
// Vt: [B*D][S] bf16 (pre-transposed by the V-projection GEMM).
// Block = (b, h, 128 q-rows); 8 waves x 16 q-rows each (QBLK=128 amortizes
// the K/V^T tiles over 2x the q-rows and raises waves/CU for latency hiding).
// Double-buffered K/V^T LDS tiles; prefetch issued BEFORE compute; one
// vmcnt(0)+s_barrier per tile.
// Swapped QK^T: sacc = mfma(K, Q) -> lane's 16 regs hold scores of ONE q-row
// (l15): kv = ct*16 + lhi*4 + jj.
// Row sums via ones-column MFMA: lsum[jj] = sum_kv P[row lhi*4+jj][kv] --
// same register layout as xacc, so rescale and final 1/l need NO shuffles.
// Defer-max (THR=8): per-lane check first; cross-lane max reduce only on
// the rare rescale tile.
__global__ void __launch_bounds__(512, 4) attn_kernel(
    const unsigned short* __restrict__ Q, const unsigned short* __restrict__ Kk,
    const unsigned short* __restrict__ Vt, unsigned short* __restrict__ X) {
  __shared__ unsigned short lK[2][64 * 64];   // [kv][dk], XOR-swizzled (both-sides)
  __shared__ unsigned short lVT[2][64 * 64];  // [dk][kv], XOR-swizzled
  __shared__ unsigned short lP[8 * 16 * 64];  // per-wave [16][64], XOR-swizzled
  const int t = threadIdx.x;
  const int wv = t >> 6, ln = t & 63;
  const int l15 = ln & 15, lhi = ln >> 4;
  const int q0 = blockIdx.x * 128;
  const int h = blockIdx.y, b = blockIdx.z;
  const size_t base = (size_t)b * Sc * Dc;
  const int hoff = h * DKc;

  bf16x8 qf[2];
  {
    const unsigned short* qp = Q + base + (size_t)(q0 + wv * 16 + l15) * Dc + hoff + lhi * 8;
    qf[0] = *reinterpret_cast<const bf16x8*>(qp);
    qf[1] = *reinterpret_cast<const bf16x8*>(qp + 32);
  }

  // staging: 512 threads x 16B = one full 64x64 bf16 tile per buffer.
  // LDS dest LINEAR (global_load_lds constraint); swizzle applied on SOURCE col.
  const int e0 = t * 8;
  const int r0 = e0 >> 6, c0 = (e0 & 63) ^ ((r0 & 7) << 3);
  const unsigned short* kS0 = Kk + base + (size_t)r0 * Dc + hoff + c0;
  const unsigned short* vS0 = Vt + ((size_t)b * Dc + hoff + r0) * Sc + c0;

  float mrow = -1e30f;            // running max for q-row l15 (x4 replicated)
  f32x4 xacc[4] = {};             // out rows lhi*4+jj, cols dt*16+l15
  f32x4 lsum = {};                // row sums for rows lhi*4+jj (ones-MFMA)
  const int swzK = (l15 & 7) << 4;

  bf16x8 ones;
#pragma unroll
  for (int i = 0; i < 8; ++i) ones[i] = (bf16_t)1.0f;

#define STAGE(bi, kv0_)                                                    \
  do {                                                                     \
    gload_lds16(kS0 + (size_t)(kv0_)*Dc, (char*)lK[bi] + e0 * 2);          \
    gload_lds16(vS0 + (kv0_), (char*)lVT[bi] + e0 * 2);                    \
  } while (0)

  STAGE(0, 0);
  asm volatile("s_waitcnt vmcnt(0)" ::: "memory");
  __builtin_amdgcn_s_barrier();
  __builtin_amdgcn_sched_barrier(0);

  for (int tt = 0; tt < Sc / 64; ++tt) {
    const int cur = tt & 1;
    if (tt + 1 < Sc / 64) STAGE(cur ^ 1, (tt + 1) * 64); // prefetch next tile

    const unsigned short* K_ = lK[cur];
    const unsigned short* VT_ = lVT[cur];

    // swapped QK^T: sacc[ct][jj] = S[kv0 + ct*16 + lhi*4 + jj][q-row l15]
    f32x4 sacc[4];
#pragma unroll
    for (int ct = 0; ct < 4; ++ct) {
      f32x4 z = {};
#pragma unroll
      for (int kk = 0; kk < 2; ++kk) {
        bf16x8 kf = *reinterpret_cast<const bf16x8*>(
            (const char*)K_ + (((ct * 16 + l15) * 128 + kk * 64 + lhi * 16) ^ swzK));
        z = __builtin_amdgcn_mfma_f32_16x16x32_bf16(kf, qf[kk], z, 0, 0, 0);
      }
      sacc[ct] = z;
    }

    // per-lane max over this lane's 16 scores (no cross-lane yet)
    float mt = fmaxf(fmaxf(sacc[0][0], sacc[0][1]), fmaxf(sacc[0][2], sacc[0][3]));
#pragma unroll
    for (int ct = 1; ct < 4; ++ct)
      mt = fmaxf(mt,
          fmaxf(fmaxf(sacc[ct][0], sacc[ct][1]), fmaxf(sacc[ct][2], sacc[ct][3])));

    // defer-max: rescale only when some lane's max grew past threshold.
    // Stale m keeps P <= 2^8 = 256 — fine in f32 accum / bf16 P.
    if (__any(mt > mrow + 8.0f)) {
      float mtr = fmaxf(mt, __shfl_xor(mt, 16));
      mtr = fmaxf(mtr, __shfl_xor(mtr, 32)); // row max (lanes sharing l15)
      float mnew = fmaxf(mrow, mtr);
      float corr = fexp2(mrow - mnew);
      mrow = mnew;
#pragma unroll
      for (int jj = 0; jj < 4; ++jj) {
        float cO = __shfl(corr, lhi * 4 + jj); // corr of q-row lhi*4+jj
        lsum[jj] *= cO;
#pragma unroll
        for (int dt = 0; dt < 4; ++dt) xacc[dt][jj] *= cO;
      }
    }

    // P = exp2(S - mrow), straight to bf16 + LDS (row sums come from MFMA)
#pragma unroll
    for (int ct = 0; ct < 4; ++ct) {
      bf16x4 pv;
#pragma unroll
      for (int jj = 0; jj < 4; ++jj)
        pv[jj] = (bf16_t)fexp2(sacc[ct][jj] - mrow);
      *reinterpret_cast<bf16x4*>(
          (char*)lP + ((wv * 2048 + l15 * 128 + ct * 32 + lhi * 8) ^ swzK)) = pv;
    }

    // PV: xacc[dt] += P(16x64) @ V^T(64x16); lsum += P @ ones
#pragma unroll
    for (int kk = 0; kk < 2; ++kk) {
      bf16x8 pa = *reinterpret_cast<const bf16x8*>(
          (char*)lP + ((wv * 2048 + l15 * 128 + kk * 64 + lhi * 16) ^ swzK));
      lsum = __builtin_amdgcn_mfma_f32_16x16x32_bf16(pa, ones, lsum, 0, 0, 0);
#pragma unroll
      for (int dt = 0; dt < 4; ++dt) {
        bf16x8 vb = *reinterpret_cast<const bf16x8*>(
            (const char*)VT_ + (((dt * 16 + l15) * 128 + kk * 64 + lhi * 16) ^ swzK));
        xacc[dt] = __builtin_amdgcn_mfma_f32_16x16x32_bf16(pa, vb, xacc[dt], 0, 0, 0);
      }
    }

    // single drain+barrier per tile
    asm volatile("s_waitcnt vmcnt(0)" ::: "memory");
    __builtin_amdgcn_s_barrier();
    __builtin_amdgcn_sched_barrier(0);
  }
#undef STAGE

  // lsum[jj] is already the row sum for output row lhi*4+jj — no shuffles.
  float iO[4];
#pragma unroll
  for (int jj = 0; jj < 4; ++jj) iO[jj] = 1.0f / lsum[jj];

  unsigned short* xp = X + base + (size_t)(q0 + wv * 16) * Dc + hoff;
#pragma unroll
  for (int dt = 0; dt < 4; ++dt)
#pragma unroll
    for (int jj = 0; jj < 4; ++jj) {
      int r = lhi * 4 + jj;
      xp[(size_t)r * Dc + dt * 16 + l15] = f2bf(xacc[dt][jj] * iO[jj]);
    }
}

// ---------------- launch ----------------
extern "C" void kernel_launch(void* const* d_in, const int* in_sizes, int n_in,
                              void* d_out, int out_size, void* d_ws, size_t ws_size,
                              hipStream_t stream) {
  const float* query = (const float*)d_in[0];
  const float* key   = (const float*)d_in[1];
  const float* value = (const float*)d_in[2];
  const float* Wq = (const float*)d_in[3];
  const float* bq = (const float*)d_in[4];
  const float* Wk = (const float*)d_in[5];
  const float* bk = (const float*)d_in[6];
  const float* Wv = (const float*)d_in[7];
  const float* bv = (const float*)d_in[8];
  const float* Wo = (const float*)d_in[9];
  const float* bo = (const float*)d_in[10];

  const size_t NBS = (size_t)Mrows * Dc; // 8388608
  const size_t NW  = (size_t)Dc * Dc;    // 1048576
  unsigned short* bQin = (unsigned short*)d_ws;
  unsigned short* bKin = bQin + NBS;
  unsigned short* bVin = bKin + NBS;
  unsigned short* bWq  = bVin + NBS;
  unsigned short* bWk  = bWq + NW;
  unsigned short* bWv  = bWk + NW;
  unsigned short* bWo  = bWv + NW;
  unsigned short* Qp   = bWo + NW;
  unsigned short* Kp   = Qp + NBS;
  unsigned short* Vtp  = Kp + NBS; // V projection stored TRANSPOSED: [B*D][S]
  unsigned short* Xp   = Vtp + NBS;

  cvt_bf16_kernel<<<(int)(NBS / 1024), 256, 0, stream>>>(query, bQin, (int)(NBS / 4));
  cvt_bf16_kernel<<<(int)(NBS / 1024), 256, 0, stream>>>(key,   bKin, (int)(NBS / 4));
  cvt_bf16_kernel<<<(int)(NBS / 1024), 256, 0, stream>>>(value, bVin, (int)(NBS / 4));
  cvt_bf16_kernel<<<(int)(NW / 1024),  256, 0, stream>>>(Wq, bWq, (int)(NW / 4));
  cvt_bf16_kernel<<<(int)(NW / 1024),  256, 0, stream>>>(Wk, bWk, (int)(NW / 4));
  cvt_bf16_kernel<<<(int)(NW / 1024),  256, 0, stream>>>(Wv, bWv, (int)(NW / 4));
  cvt_bf16_kernel<<<(int)(NW / 1024),  256, 0, stream>>>(Wo, bWo, (int)(NW / 4));

  dim3 gg(Dc / 128, Mrows / 128); // (8, 64)
  // Q prescale folds 1/sqrt(DK) AND log2(e) (attn softmax runs in exp2 domain)
  gemm_bt_kernel<1><<<gg, 256, 0, stream>>>(bQin, bWq, bq, Qp, Mrows, Dc, Dc,
                                            0.125f * 1.44269504088896340736f);
  gemm_bt_kernel<1><<<gg, 256, 0, stream>>>(bKin, bWk, bk, Kp, Mrows, Dc, Dc, 1.0f);
  gemm_bt_kernel<2><<<gg, 256, 0, stream>>>(bVin, bWv, bv, Vtp, Mrows, Dc, Dc, 1.0f);

  attn_kernel<<<dim3(Sc / 128, Hc, Bc), 512, 0, stream>>>(Qp, Kp, Vtp, Xp);

  gemm_bt_kernel<0><<<gg, 256, 0, stream>>>(Xp, bWo, bo, d_out, Mrows, Dc, Dc, 1.0f);
}